// Round 15
// baseline (84.714 us; speedup 1.0000x reference)
//
#include <hip/hip_runtime.h>
#include <math.h>

#define Bn 64
#define Pn 8732
#define Cn 21
#define NMAXn 50
#define PX 35  // ceil(Pn/256)

// ---------------- DPP wave64 reduces (VALU pipe, not LDS) -------------------
template <int C>
__device__ __forceinline__ float dppf(float x) {
    return __int_as_float(__builtin_amdgcn_update_dpp(0, __float_as_int(x), C, 0xf, 0xf, true));
}
template <int C>
__device__ __forceinline__ int dppi(int x) {
    return __builtin_amdgcn_update_dpp(0, x, C, 0xf, 0xf, true);
}
__device__ __forceinline__ float wave_sum_f(float x) {
    x += dppf<0x111>(x); x += dppf<0x112>(x); x += dppf<0x114>(x);
    x += dppf<0x118>(x); x += dppf<0x142>(x); x += dppf<0x143>(x);
    return x;  // lane 63
}
__device__ __forceinline__ int wave_sum_i(int x) {
    x += dppi<0x111>(x); x += dppi<0x112>(x); x += dppi<0x114>(x);
    x += dppi<0x118>(x); x += dppi<0x142>(x); x += dppi<0x143>(x);
    return x;  // lane 63
}

__device__ __forceinline__ float smoothl1_enc(const float4 l, const float4 pr,
                                              float gx0, float gy0, float gx1, float gy1) {
    const float tx = ((gx0 + gx1) * 0.5f - pr.x) / (0.1f * pr.z);
    const float ty = ((gy0 + gy1) * 0.5f - pr.y) / (0.1f * pr.w);
    const float tw = __logf((gx1 - gx0) / pr.z) * 5.0f;  // /0.2
    const float th = __logf((gy1 - gy0) / pr.w) * 5.0f;
    float s = 0.0f, d;
    d = fabsf(l.x - tx); s += (d < 1.0f) ? 0.5f * d * d : d - 0.5f;
    d = fabsf(l.y - ty); s += (d < 1.0f) ? 0.5f * d * d : d - 0.5f;
    d = fabsf(l.z - tw); s += (d < 1.0f) ? 0.5f * d * d : d - 0.5f;
    d = fabsf(l.w - th); s += (d < 1.0f) ? 0.5f * d * d : d - 0.5f;
    return s;
}

// IoU numerator/denominator (no divide). All >= 0.
#define IOU_IU(gx0, gy0, gx1, gy1, qx0, qy0, qx1, qy1, qarea, I, U)            \
    {                                                                          \
        const float lx = fmaxf(gx0, qx0), ly = fmaxf(gy0, qy0);                \
        const float rx = fminf(gx1, qx1), ry = fminf(gy1, qy1);                \
        const float w = fmaxf(rx - lx, 0.0f), h = fmaxf(ry - ly, 0.0f);        \
        I = w * h;                                                             \
        U = (gx1 - gx0) * (gy1 - gy0) + qarea - I;                             \
    }

// ---------------------------------------------------------------------------
// K1, two roles in one dispatch. Division-free cross-mult comparator with
// DUAL-TRACKER unroll (evens/odds) to halve the loop-carried compare chain.
// Combine rule: product tie -> min index == first-occurrence argmax.
// ---------------------------------------------------------------------------
__global__ __launch_bounds__(256) void k_fused(const float* __restrict__ conf,
                                               const float* __restrict__ loc,
                                               const float* __restrict__ priors,
                                               const float* __restrict__ labels,
                                               const int* __restrict__ objc,
                                               float* __restrict__ lc,
                                               float* __restrict__ part_loc,
                                               float* __restrict__ part_nll,
                                               int* __restrict__ part_np,
                                               int* __restrict__ sbp_g,
                                               int* __restrict__ done) {
    const int bx = blockIdx.x;
    const int tid = threadIdx.x;
    const int lane = tid & 63, wid = tid >> 6;
    if (bx == 0 && tid == 0) *done = 0;  // ordered before k_negfix by kernel boundary

    __shared__ float sconf[256 * Cn];  // 21504 B (role A)
    __shared__ float lab[NMAXn * 5];
    __shared__ float rl[4], rn[4];
    __shared__ int rp[4];
    __shared__ float wkI[4], wkU[4];   // role B
    __shared__ int wkP[4];

    if (bx < Bn * PX) {
        // ================= Role A: match + main =================
        const int b = bx / PX;
        const int px = bx % PX;
        const int p0 = px * 256;
        const int rows = min(256, Pn - p0);
        const int cnt = objc[b];                  // uniform -> scalar
        const float* lb = labels + b * NMAXn * 5;

        const float4* src = reinterpret_cast<const float4*>(conf + ((size_t)b * Pn + p0) * Cn);
        const int n4 = rows * Cn / 4;  // rows*21 divisible by 4 for rows in {256,28}
        for (int i = tid; i < n4; i += 256) reinterpret_cast<float4*>(sconf)[i] = src[i];
        for (int i = tid; i < NMAXn * 5; i += 256) lab[i] = labels[b * NMAXn * 5 + i];

        const int p = p0 + tid;
        const int pcl = (p < Pn) ? p : (Pn - 1);
        const float4 pr = reinterpret_cast<const float4*>(priors)[pcl];
        const float px0 = pr.x - 0.5f * pr.z, py0 = pr.y - 0.5f * pr.w;
        const float px1 = pr.x + 0.5f * pr.z, py1 = pr.y + 0.5f * pr.w;
        const float parea = (px1 - px0) * (py1 - py0);
        // dual trackers: t0 evens, t1 odds. Neutral (0,1,idx0) loses to any I>0;
        // all-zero ties resolve to idx 0 via combine (== reference argmax).
        float bI0 = 0.0f, bU0 = 1.0f, bI1 = 0.0f, bU1 = 1.0f;
        int bx0 = 0, bx1 = 0;
        int n = 0;
        for (; n + 1 < cnt; n += 2) {
            float I0, U0, I1, U1;
            IOU_IU(lb[n * 5 + 0], lb[n * 5 + 1], lb[n * 5 + 2], lb[n * 5 + 3],
                   px0, py0, px1, py1, parea, I0, U0);
            IOU_IU(lb[(n + 1) * 5 + 0], lb[(n + 1) * 5 + 1], lb[(n + 1) * 5 + 2],
                   lb[(n + 1) * 5 + 3], px0, py0, px1, py1, parea, I1, U1);
            if (I0 * bU0 > bI0 * U0) { bI0 = I0; bU0 = U0; bx0 = n; }
            if (I1 * bU1 > bI1 * U1) { bI1 = I1; bU1 = U1; bx1 = n + 1; }
        }
        if (n < cnt) {  // odd tail -> t0
            float I0, U0;
            IOU_IU(lb[n * 5 + 0], lb[n * 5 + 1], lb[n * 5 + 2], lb[n * 5 + 3],
                   px0, py0, px1, py1, parea, I0, U0);
            if (I0 * bU0 > bI0 * U0) { bI0 = I0; bU0 = U0; bx0 = n; }
        }
        {   // combine: product tie -> min index (global first-occurrence)
            const float a = bI1 * bU0, c = bI0 * bU1;
            if (a > c || (a == c && bx1 < bx0)) { bI0 = bI1; bU0 = bU1; bx0 = bx1; }
        }
        __syncthreads();  // sconf, lab ready

        float my_loc = 0.0f, my_nll = 0.0f;
        int my_np = 0;
        if (tid < rows) {
            const size_t gi = (size_t)b * Pn + p;
            const int ct = (2.0f * bI0 >= bU0) ? ((int)lab[bx0 * 5 + 4] + 1) : 0;
            const float* row = sconf + tid * Cn;  // stride 21: odd -> conflict-benign
            float m = row[0];
#pragma unroll
            for (int j = 1; j < Cn; ++j) m = fmaxf(m, row[j]);
            float s2 = 0.0f;
#pragma unroll
            for (int j = 0; j < Cn; ++j) s2 += __expf(row[j] - m);
            const float nll = __logf(s2) + m - row[ct];
            if (ct > 0) {
                lc[gi] = 0.0f;
                my_np = 1;
                my_nll = nll;
                const float4 l = reinterpret_cast<const float4*>(loc)[gi];
                my_loc = smoothl1_enc(l, pr, lab[bx0 * 5 + 0], lab[bx0 * 5 + 1],
                                      lab[bx0 * 5 + 2], lab[bx0 * 5 + 3]);
            } else {
                lc[gi] = nll;
            }
        }
        my_loc = wave_sum_f(my_loc);
        my_nll = wave_sum_f(my_nll);
        my_np = wave_sum_i(my_np);
        if (lane == 63) { rl[wid] = my_loc; rn[wid] = my_nll; rp[wid] = my_np; }
        __syncthreads();
        if (tid == 0) {
            const int g = b * PX + px;
            part_loc[g] = rl[0] + rl[1] + rl[2] + rl[3];
            part_nll[g] = rn[0] + rn[1] + rn[2] + rn[3];
            part_np[g] = rp[0] + rp[1] + rp[2] + rp[3];
        }
    } else {
        // ================= Role B: block-per-GT best-prior =================
        const int idx = bx - Bn * PX;
        const int b = idx / NMAXn;
        const int n = idx % NMAXn;
        if (n >= objc[b]) return;  // uniform per block
        const float* lbp = labels + (b * NMAXn + n) * 5;
        const float gx0 = lbp[0], gy0 = lbp[1], gx1 = lbp[2], gy1 = lbp[3];
        // dual trackers over j (evens/odds). Init by j=0 / j=1 evals (always valid).
        float bI0, bU0, bI1, bU1;
        int bp0, bp1;
        {
            const float4 pr = reinterpret_cast<const float4*>(priors)[tid];
            const float qx0 = pr.x - 0.5f * pr.z, qy0 = pr.y - 0.5f * pr.w;
            const float qx1 = pr.x + 0.5f * pr.z, qy1 = pr.y + 0.5f * pr.w;
            IOU_IU(gx0, gy0, gx1, gy1, qx0, qy0, qx1, qy1,
                   (qx1 - qx0) * (qy1 - qy0), bI0, bU0);
            bp0 = tid;
        }
        {
            const float4 pr = reinterpret_cast<const float4*>(priors)[tid + 256];
            const float qx0 = pr.x - 0.5f * pr.z, qy0 = pr.y - 0.5f * pr.w;
            const float qx1 = pr.x + 0.5f * pr.z, qy1 = pr.y + 0.5f * pr.w;
            IOU_IU(gx0, gy0, gx1, gy1, qx0, qy0, qx1, qy1,
                   (qx1 - qx0) * (qy1 - qy0), bI1, bU1);
            bp1 = tid + 256;
        }
        int j = 2;
        for (; j + 1 < PX; j += 2) {  // j <= 33: p <= 255+256*33 = 8703 < Pn, no guard
            const int pA = tid + 256 * j, pB = pA + 256;
            float IA, UA, IB, UB;
            {
                const float4 pr = reinterpret_cast<const float4*>(priors)[pA];
                const float qx0 = pr.x - 0.5f * pr.z, qy0 = pr.y - 0.5f * pr.w;
                const float qx1 = pr.x + 0.5f * pr.z, qy1 = pr.y + 0.5f * pr.w;
                IOU_IU(gx0, gy0, gx1, gy1, qx0, qy0, qx1, qy1,
                       (qx1 - qx0) * (qy1 - qy0), IA, UA);
            }
            {
                const float4 pr = reinterpret_cast<const float4*>(priors)[pB];
                const float qx0 = pr.x - 0.5f * pr.z, qy0 = pr.y - 0.5f * pr.w;
                const float qx1 = pr.x + 0.5f * pr.z, qy1 = pr.y + 0.5f * pr.w;
                IOU_IU(gx0, gy0, gx1, gy1, qx0, qy0, qx1, qy1,
                       (qx1 - qx0) * (qy1 - qy0), IB, UB);
            }
            if (IA * bU0 > bI0 * UA) { bI0 = IA; bU0 = UA; bp0 = pA; }
            if (IB * bU1 > bI1 * UB) { bI1 = IB; bU1 = UB; bp1 = pB; }
        }
        {   // tail j = 34 (guarded: p < Pn iff tid < 28)
            const int pA = tid + 256 * 34;
            if (pA < Pn) {
                const float4 pr = reinterpret_cast<const float4*>(priors)[pA];
                const float qx0 = pr.x - 0.5f * pr.z, qy0 = pr.y - 0.5f * pr.w;
                const float qx1 = pr.x + 0.5f * pr.z, qy1 = pr.y + 0.5f * pr.w;
                float IA, UA;
                IOU_IU(gx0, gy0, gx1, gy1, qx0, qy0, qx1, qy1,
                       (qx1 - qx0) * (qy1 - qy0), IA, UA);
                if (IA * bU0 > bI0 * UA) { bI0 = IA; bU0 = UA; bp0 = pA; }
            }
        }
        {   // combine trackers: product tie -> min p
            const float a = bI1 * bU0, c = bI0 * bU1;
            if (a > c || (a == c && bp1 < bp0)) { bI0 = bI1; bU0 = bU1; bp0 = bp1; }
        }
        // wave reduce of (I,U,p): product comparison, tie -> min p
        for (int off = 32; off > 0; off >>= 1) {
            const float oI = __shfl_down(bI0, off);
            const float oU = __shfl_down(bU0, off);
            const int op = __shfl_down(bp0, off);
            const float a = oI * bU0, c = bI0 * oU;
            if (a > c || (a == c && op < bp0)) { bI0 = oI; bU0 = oU; bp0 = op; }
        }
        if (lane == 0) { wkI[wid] = bI0; wkU[wid] = bU0; wkP[wid] = bp0; }
        __syncthreads();
        if (tid == 0) {
            float cI = wkI[0], cU = wkU[0];
            int cp = wkP[0];
#pragma unroll
            for (int w = 1; w < 4; ++w) {
                const float a = wkI[w] * cU, c = cI * wkU[w];
                if (a > c || (a == c && wkP[w] < cp)) { cI = wkI[w]; cU = wkU[w]; cp = wkP[w]; }
            }
            sbp_g[b * NMAXn + n] = cp;
        }
    }
}

// ---------------------------------------------------------------------------
// K2 = merged fixup + hard-negative top-k + final reduce. Per batch b:
//  - all threads issue lc register loads (12 float4)
//  - wave 0: stage labels+sbp, last-n-wins, forced-delta recompute (cross-mult
//    comparator, identical to K1), publish flist to LDS + fix_* to global
//  - wave 1: reduce num_pos from part_np (parallel with wave 0)
//  - all: mask forced entries in-register (flist broadcast, unrolled slots)
//  - 31-iter bisection on float bits (exact) with k = 3*(np+dnp)
//  - last block (done counter): final reduce incl. fix terms -> out[0..1]
// ---------------------------------------------------------------------------
__global__ __launch_bounds__(256) void k_negfix(const float* __restrict__ conf,
                                                const float* __restrict__ loc,
                                                const float* __restrict__ priors,
                                                const float* __restrict__ labels,
                                                const int* __restrict__ objc,
                                                const int* __restrict__ sbp_g,
                                                const float* __restrict__ lc,
                                                const float* __restrict__ part_loc,
                                                const float* __restrict__ part_nll,
                                                const int* __restrict__ part_np,
                                                int* __restrict__ fix_np,
                                                float* __restrict__ fix_nll,
                                                float* __restrict__ fix_loc,
                                                float* __restrict__ negsum,
                                                int* __restrict__ done,
                                                float* __restrict__ out) {
    const int b = blockIdx.x;
    const int tid = threadIdx.x;
    const int lane = tid & 63, wid = tid >> 6;
    __shared__ float lab[NMAXn * 5];
    __shared__ int sbp[NMAXn];
    __shared__ int flist[NMAXn];
    __shared__ int fcnt_s, dnp_s;
    __shared__ int redc[2][4];
    __shared__ float redf[4], redf2[4];
    __shared__ int redi[4];
    __shared__ int np_sh, islast;

    const int NV = Pn / 4;  // 2183 float4s exactly
    const float4* src = reinterpret_cast<const float4*>(lc + (size_t)b * Pn);
    const float4 sent = make_float4(-1.0f, -1.0f, -1.0f, -1.0f);
    float4 rr[12];
#pragma unroll
    for (int j = 0; j < 12; ++j) {
        const int i = tid + 256 * j;
        rr[j] = (i < NV) ? src[i] : sent;
    }

    const int cnt = objc[b];
    if (tid < 64) {  // wave 0: stage fix inputs
        for (int i = tid; i < NMAXn * 5; i += 64) lab[i] = labels[b * NMAXn * 5 + i];
        if (tid < cnt) sbp[tid] = sbp_g[b * NMAXn + tid];
    } else if (tid < 128) {  // wave 1: num_pos reduce (parallel with wave 0)
        const int t = tid - 64;
        int npl = (t < PX) ? part_np[b * PX + t] : 0;
        npl = wave_sum_i(npl);
        if (t == 63) np_sh = npl;
    }
    __syncthreads();

    if (tid < 64) {  // wave 0: last-n-wins + forced deltas
        bool win = false;
        if (tid < cnt) {
            const int myp = sbp[tid];
            win = true;
            for (int n2 = tid + 1; n2 < cnt; ++n2) win = win && (sbp[n2] != myp);
        }
        const unsigned long long wmask = __ballot(win);
        float dnll = 0.0f, dloc = 0.0f;
        int dnp = 0;
        if (win) {
            const int pp = sbp[tid];
            const float4 prf = reinterpret_cast<const float4*>(priors)[pp];
            const float qx0 = prf.x - 0.5f * prf.z, qy0 = prf.y - 0.5f * prf.w;
            const float qx1 = prf.x + 0.5f * prf.z, qy1 = prf.y + 0.5f * prf.w;
            const float qarea = (qx1 - qx0) * (qy1 - qy0);
            float bI = 0.0f, bU = 1.0f;
            int bidx2 = 0;
            for (int n2 = 0; n2 < cnt; ++n2) {  // sequential == K1's combined order
                float I, U;
                IOU_IU(lab[n2 * 5 + 0], lab[n2 * 5 + 1], lab[n2 * 5 + 2],
                       lab[n2 * 5 + 3], qx0, qy0, qx1, qy1, qarea, I, U);
                if (I * bU > bI * U) { bI = I; bU = U; bidx2 = n2; }
            }
            const float* rowg = conf + ((size_t)b * Pn + pp) * Cn;
            float m2 = rowg[0];
#pragma unroll
            for (int j = 1; j < Cn; ++j) m2 = fmaxf(m2, rowg[j]);
            float ss = 0.0f;
#pragma unroll
            for (int j = 0; j < Cn; ++j) ss += __expf(rowg[j] - m2);
            const float lse = __logf(ss) + m2;
            const int ctn = (int)lab[tid * 5 + 4] + 1;
            const float4 lv = reinterpret_cast<const float4*>(loc)[(size_t)b * Pn + pp];
            dnll = lse - rowg[ctn];
            dloc = smoothl1_enc(lv, prf, lab[tid * 5 + 0], lab[tid * 5 + 1],
                                lab[tid * 5 + 2], lab[tid * 5 + 3]);
            dnp = 1;
            if (2.0f * bI >= bU) {  // old was positive: subtract its old contribution
                const int cto = (int)lab[bidx2 * 5 + 4] + 1;
                dnll -= (lse - rowg[cto]);
                dloc -= smoothl1_enc(lv, prf, lab[bidx2 * 5 + 0], lab[bidx2 * 5 + 1],
                                     lab[bidx2 * 5 + 2], lab[bidx2 * 5 + 3]);
                dnp = 0;
            }
            const int sidx = __popcll(wmask & ((1ull << lane) - 1));
            flist[sidx] = pp;
        }
        dnll = wave_sum_f(dnll);
        dloc = wave_sum_f(dloc);
        dnp = wave_sum_i(dnp);
        if (tid == 63) {
            fix_nll[b] = dnll;
            fix_loc[b] = dloc;
            fix_np[b] = dnp;
            dnp_s = dnp;
            fcnt_s = (int)__popcll(wmask);
        }
    }
    __syncthreads();

    // mask forced priors in-register (they are positives)
    const int fcnt = fcnt_s;
    for (int i = 0; i < fcnt; ++i) {
        const int pp = flist[i];  // broadcast LDS read
#pragma unroll
        for (int j = 0; j < 12; ++j) {
            const int base = (tid + 256 * j) << 2;
            if (pp >= base && pp < base + 4) {
                if (pp == base) rr[j].x = 0.0f;
                else if (pp == base + 1) rr[j].y = 0.0f;
                else if (pp == base + 2) rr[j].z = 0.0f;
                else rr[j].w = 0.0f;
            }
        }
    }
    const int k = min(3 * (np_sh + dnp_s), Pn - 1);

    unsigned lo = 0u, hi = 0x7F800000u;
#pragma unroll 1
    for (int it = 0; it < 31; ++it) {
        const unsigned mid = lo + ((hi - lo) >> 1);
        const float fm = __uint_as_float(mid);  // fm >= 0: sentinels never counted
        int c = 0;
#pragma unroll
        for (int j = 0; j < 12; ++j)
            c += (rr[j].x >= fm) + (rr[j].y >= fm) + (rr[j].z >= fm) + (rr[j].w >= fm);
        c = wave_sum_i(c);
        if (lane == 63) redc[it & 1][wid] = c;
        __syncthreads();
        const int tot = redc[it & 1][0] + redc[it & 1][1]
                      + redc[it & 1][2] + redc[it & 1][3];
        if (tot >= k) lo = mid;
        else hi = mid;
    }
    const float v = __uint_as_float(lo);  // exact k-th largest value

    float sm = 0.0f;
    int c = 0;
#pragma unroll
    for (int j = 0; j < 12; ++j) {
        if (rr[j].x > v) { sm += rr[j].x; ++c; }
        if (rr[j].y > v) { sm += rr[j].y; ++c; }
        if (rr[j].z > v) { sm += rr[j].z; ++c; }
        if (rr[j].w > v) { sm += rr[j].w; ++c; }
    }
    sm = wave_sum_f(sm);
    c = wave_sum_i(c);
    if (lane == 63) { redf[wid] = sm; redi[wid] = c; }
    __syncthreads();
    if (tid == 0) {
        const float st = redf[0] + redf[1] + redf[2] + redf[3];
        const int ct = redi[0] + redi[1] + redi[2] + redi[3];
        negsum[b] = st + (float)(k - ct) * v;  // exact tie handling at boundary
        __threadfence();
        islast = (atomicAdd(done, 1) == Bn - 1) ? 1 : 0;
    }
    __syncthreads();
    if (!islast) return;
    __threadfence();  // acquire: other blocks' stores precede their fenced atomics

    // ---- fused final reduce (exactly one block runs this) ----
    float sl = 0.0f, sn = 0.0f;
    int np = 0;
    for (int i = tid; i < Bn * PX; i += 256) {
        sl += part_loc[i];
        sn += part_nll[i];
        np += part_np[i];
    }
    if (tid < Bn) {
        sn += negsum[tid] + fix_nll[tid];
        sl += fix_loc[tid];
        np += fix_np[tid];
    }
    sl = wave_sum_f(sl);
    sn = wave_sum_f(sn);
    np = wave_sum_i(np);
    if (lane == 63) { redf[wid] = sn; redf2[wid] = sl; redi[wid] = np; }
    __syncthreads();
    if (tid == 0) {
        const float fN = (float)(redi[0] + redi[1] + redi[2] + redi[3]);
        out[0] = (redf2[0] + redf2[1] + redf2[2] + redf2[3]) / fN;
        out[1] = (redf[0] + redf[1] + redf[2] + redf[3]) / fN;
    }
}

extern "C" void kernel_launch(void* const* d_in, const int* in_sizes, int n_in,
                              void* d_out, int out_size, void* d_ws, size_t ws_size,
                              hipStream_t stream) {
    const float* conf = (const float*)d_in[0];
    const float* loc = (const float*)d_in[1];
    const float* priors = (const float*)d_in[2];
    const float* labels = (const float*)d_in[3];
    const int* objc = (const int*)d_in[4];
    float* out = (float*)d_out;

    // ws layout: sbp_g[3200] | part_loc/nll/np[2240 each] | negsum[64] |
    //            fix_np[64] | fix_nll[64] | fix_loc[64] | lc[Bn*Pn] | done
    int* sbp_g = (int*)d_ws;
    float* part_loc = (float*)(sbp_g + Bn * NMAXn);
    float* part_nll = part_loc + Bn * PX;
    int* part_np = (int*)(part_nll + Bn * PX);
    float* negsum = (float*)(part_np + Bn * PX);
    int* fix_np = (int*)(negsum + Bn);
    float* fix_nll = (float*)(fix_np + Bn);
    float* fix_loc = fix_nll + Bn;
    float* lc = fix_loc + Bn;
    int* done = (int*)(lc + (size_t)Bn * Pn);

    k_fused<<<Bn * PX + Bn * NMAXn, 256, 0, stream>>>(conf, loc, priors, labels, objc,
                                                      lc, part_loc, part_nll, part_np,
                                                      sbp_g, done);
    k_negfix<<<Bn, 256, 0, stream>>>(conf, loc, priors, labels, objc, sbp_g, lc,
                                     part_loc, part_nll, part_np,
                                     fix_np, fix_nll, fix_loc, negsum, done, out);
}

// Round 16
// 67.494 us; speedup vs baseline: 1.2551x; 1.2551x over previous
//
#include <hip/hip_runtime.h>
#include <math.h>

#define Bn 64
#define Pn 8732
#define Cn 21
#define NMAXn 50
#define PX 35  // ceil(Pn/256)

// ---------------- DPP wave64 reduces (VALU pipe, not LDS) -------------------
template <int C>
__device__ __forceinline__ float dppf(float x) {
    return __int_as_float(__builtin_amdgcn_update_dpp(0, __float_as_int(x), C, 0xf, 0xf, true));
}
template <int C>
__device__ __forceinline__ int dppi(int x) {
    return __builtin_amdgcn_update_dpp(0, x, C, 0xf, 0xf, true);
}
__device__ __forceinline__ float wave_sum_f(float x) {
    x += dppf<0x111>(x); x += dppf<0x112>(x); x += dppf<0x114>(x);
    x += dppf<0x118>(x); x += dppf<0x142>(x); x += dppf<0x143>(x);
    return x;  // lane 63
}
__device__ __forceinline__ int wave_sum_i(int x) {
    x += dppi<0x111>(x); x += dppi<0x112>(x); x += dppi<0x114>(x);
    x += dppi<0x118>(x); x += dppi<0x142>(x); x += dppi<0x143>(x);
    return x;  // lane 63
}

__device__ __forceinline__ float smoothl1_enc(const float4 l, const float4 pr,
                                              float gx0, float gy0, float gx1, float gy1) {
    const float tx = ((gx0 + gx1) * 0.5f - pr.x) / (0.1f * pr.z);
    const float ty = ((gy0 + gy1) * 0.5f - pr.y) / (0.1f * pr.w);
    const float tw = __logf((gx1 - gx0) / pr.z) * 5.0f;  // /0.2
    const float th = __logf((gy1 - gy0) / pr.w) * 5.0f;
    float s = 0.0f, d;
    d = fabsf(l.x - tx); s += (d < 1.0f) ? 0.5f * d * d : d - 0.5f;
    d = fabsf(l.y - ty); s += (d < 1.0f) ? 0.5f * d * d : d - 0.5f;
    d = fabsf(l.z - tw); s += (d < 1.0f) ? 0.5f * d * d : d - 0.5f;
    d = fabsf(l.w - th); s += (d < 1.0f) ? 0.5f * d * d : d - 0.5f;
    return s;
}

// IoU numerator/denominator (no divide). All >= 0.
#define IOU_IU(gx0, gy0, gx1, gy1, qx0, qy0, qx1, qy1, qarea, I, U)            \
    {                                                                          \
        const float lx = fmaxf(gx0, qx0), ly = fmaxf(gy0, qy0);                \
        const float rx = fminf(gx1, qx1), ry = fminf(gy1, qy1);                \
        const float w = fmaxf(rx - lx, 0.0f), h = fmaxf(ry - ly, 0.0f);        \
        I = w * h;                                                             \
        U = (gx1 - gx0) * (gy1 - gy0) + qarea - I;                             \
    }

// ---------------------------------------------------------------------------
// K1, two roles in one dispatch. Division-free cross-mult comparator with
// DUAL-TRACKER unroll (evens/odds) to halve the loop-carried compare chain.
// Combine rule: product tie -> min index == first-occurrence argmax.
// ---------------------------------------------------------------------------
__global__ __launch_bounds__(256) void k_fused(const float* __restrict__ conf,
                                               const float* __restrict__ loc,
                                               const float* __restrict__ priors,
                                               const float* __restrict__ labels,
                                               const int* __restrict__ objc,
                                               float* __restrict__ lc,
                                               float* __restrict__ part_loc,
                                               float* __restrict__ part_nll,
                                               int* __restrict__ part_np,
                                               int* __restrict__ sbp_g) {
    const int bx = blockIdx.x;
    const int tid = threadIdx.x;
    const int lane = tid & 63, wid = tid >> 6;

    __shared__ float sconf[256 * Cn];  // 21504 B (role A)
    __shared__ float lab[NMAXn * 5];
    __shared__ float rl[4], rn[4];
    __shared__ int rp[4];
    __shared__ float wkI[4], wkU[4];   // role B
    __shared__ int wkP[4];

    if (bx < Bn * PX) {
        // ================= Role A: match + main =================
        const int b = bx / PX;
        const int px = bx % PX;
        const int p0 = px * 256;
        const int rows = min(256, Pn - p0);
        const int cnt = objc[b];                  // uniform -> scalar
        const float* lb = labels + b * NMAXn * 5;

        const float4* src = reinterpret_cast<const float4*>(conf + ((size_t)b * Pn + p0) * Cn);
        const int n4 = rows * Cn / 4;  // rows*21 divisible by 4 for rows in {256,28}
        for (int i = tid; i < n4; i += 256) reinterpret_cast<float4*>(sconf)[i] = src[i];
        for (int i = tid; i < NMAXn * 5; i += 256) lab[i] = labels[b * NMAXn * 5 + i];

        const int p = p0 + tid;
        const int pcl = (p < Pn) ? p : (Pn - 1);
        const float4 pr = reinterpret_cast<const float4*>(priors)[pcl];
        const float px0 = pr.x - 0.5f * pr.z, py0 = pr.y - 0.5f * pr.w;
        const float px1 = pr.x + 0.5f * pr.z, py1 = pr.y + 0.5f * pr.w;
        const float parea = (px1 - px0) * (py1 - py0);
        // dual trackers: t0 evens, t1 odds. Neutral (0,1,idx0) loses to any I>0;
        // all-zero ties resolve to idx 0 via combine (== reference argmax).
        float bI0 = 0.0f, bU0 = 1.0f, bI1 = 0.0f, bU1 = 1.0f;
        int bx0 = 0, bx1 = 0;
        int n = 0;
        for (; n + 1 < cnt; n += 2) {
            float I0, U0, I1, U1;
            IOU_IU(lb[n * 5 + 0], lb[n * 5 + 1], lb[n * 5 + 2], lb[n * 5 + 3],
                   px0, py0, px1, py1, parea, I0, U0);
            IOU_IU(lb[(n + 1) * 5 + 0], lb[(n + 1) * 5 + 1], lb[(n + 1) * 5 + 2],
                   lb[(n + 1) * 5 + 3], px0, py0, px1, py1, parea, I1, U1);
            if (I0 * bU0 > bI0 * U0) { bI0 = I0; bU0 = U0; bx0 = n; }
            if (I1 * bU1 > bI1 * U1) { bI1 = I1; bU1 = U1; bx1 = n + 1; }
        }
        if (n < cnt) {  // odd tail -> t0
            float I0, U0;
            IOU_IU(lb[n * 5 + 0], lb[n * 5 + 1], lb[n * 5 + 2], lb[n * 5 + 3],
                   px0, py0, px1, py1, parea, I0, U0);
            if (I0 * bU0 > bI0 * U0) { bI0 = I0; bU0 = U0; bx0 = n; }
        }
        {   // combine: product tie -> min index (global first-occurrence)
            const float a = bI1 * bU0, c = bI0 * bU1;
            if (a > c || (a == c && bx1 < bx0)) { bI0 = bI1; bU0 = bU1; bx0 = bx1; }
        }
        __syncthreads();  // sconf, lab ready

        float my_loc = 0.0f, my_nll = 0.0f;
        int my_np = 0;
        if (tid < rows) {
            const size_t gi = (size_t)b * Pn + p;
            const int ct = (2.0f * bI0 >= bU0) ? ((int)lab[bx0 * 5 + 4] + 1) : 0;
            const float* row = sconf + tid * Cn;  // stride 21: odd -> conflict-benign
            float m = row[0];
#pragma unroll
            for (int j = 1; j < Cn; ++j) m = fmaxf(m, row[j]);
            float s2 = 0.0f;
#pragma unroll
            for (int j = 0; j < Cn; ++j) s2 += __expf(row[j] - m);
            const float nll = __logf(s2) + m - row[ct];
            if (ct > 0) {
                lc[gi] = 0.0f;
                my_np = 1;
                my_nll = nll;
                const float4 l = reinterpret_cast<const float4*>(loc)[gi];
                my_loc = smoothl1_enc(l, pr, lab[bx0 * 5 + 0], lab[bx0 * 5 + 1],
                                      lab[bx0 * 5 + 2], lab[bx0 * 5 + 3]);
            } else {
                lc[gi] = nll;
            }
        }
        my_loc = wave_sum_f(my_loc);
        my_nll = wave_sum_f(my_nll);
        my_np = wave_sum_i(my_np);
        if (lane == 63) { rl[wid] = my_loc; rn[wid] = my_nll; rp[wid] = my_np; }
        __syncthreads();
        if (tid == 0) {
            const int g = b * PX + px;
            part_loc[g] = rl[0] + rl[1] + rl[2] + rl[3];
            part_nll[g] = rn[0] + rn[1] + rn[2] + rn[3];
            part_np[g] = rp[0] + rp[1] + rp[2] + rp[3];
        }
    } else {
        // ================= Role B: block-per-GT best-prior =================
        const int idx = bx - Bn * PX;
        const int b = idx / NMAXn;
        const int n = idx % NMAXn;
        if (n >= objc[b]) return;  // uniform per block
        const float* lbp = labels + (b * NMAXn + n) * 5;
        const float gx0 = lbp[0], gy0 = lbp[1], gx1 = lbp[2], gy1 = lbp[3];
        float bI0, bU0, bI1, bU1;
        int bp0, bp1;
        {
            const float4 pr = reinterpret_cast<const float4*>(priors)[tid];
            const float qx0 = pr.x - 0.5f * pr.z, qy0 = pr.y - 0.5f * pr.w;
            const float qx1 = pr.x + 0.5f * pr.z, qy1 = pr.y + 0.5f * pr.w;
            IOU_IU(gx0, gy0, gx1, gy1, qx0, qy0, qx1, qy1,
                   (qx1 - qx0) * (qy1 - qy0), bI0, bU0);
            bp0 = tid;
        }
        {
            const float4 pr = reinterpret_cast<const float4*>(priors)[tid + 256];
            const float qx0 = pr.x - 0.5f * pr.z, qy0 = pr.y - 0.5f * pr.w;
            const float qx1 = pr.x + 0.5f * pr.z, qy1 = pr.y + 0.5f * pr.w;
            IOU_IU(gx0, gy0, gx1, gy1, qx0, qy0, qx1, qy1,
                   (qx1 - qx0) * (qy1 - qy0), bI1, bU1);
            bp1 = tid + 256;
        }
        int j = 2;
        for (; j + 1 < PX; j += 2) {  // j <= 33: p <= 8703 < Pn, no guard
            const int pA = tid + 256 * j, pB = pA + 256;
            float IA, UA, IB, UB;
            {
                const float4 pr = reinterpret_cast<const float4*>(priors)[pA];
                const float qx0 = pr.x - 0.5f * pr.z, qy0 = pr.y - 0.5f * pr.w;
                const float qx1 = pr.x + 0.5f * pr.z, qy1 = pr.y + 0.5f * pr.w;
                IOU_IU(gx0, gy0, gx1, gy1, qx0, qy0, qx1, qy1,
                       (qx1 - qx0) * (qy1 - qy0), IA, UA);
            }
            {
                const float4 pr = reinterpret_cast<const float4*>(priors)[pB];
                const float qx0 = pr.x - 0.5f * pr.z, qy0 = pr.y - 0.5f * pr.w;
                const float qx1 = pr.x + 0.5f * pr.z, qy1 = pr.y + 0.5f * pr.w;
                IOU_IU(gx0, gy0, gx1, gy1, qx0, qy0, qx1, qy1,
                       (qx1 - qx0) * (qy1 - qy0), IB, UB);
            }
            if (IA * bU0 > bI0 * UA) { bI0 = IA; bU0 = UA; bp0 = pA; }
            if (IB * bU1 > bI1 * UB) { bI1 = IB; bU1 = UB; bp1 = pB; }
        }
        {   // tail j = 34 (guarded)
            const int pA = tid + 256 * 34;
            if (pA < Pn) {
                const float4 pr = reinterpret_cast<const float4*>(priors)[pA];
                const float qx0 = pr.x - 0.5f * pr.z, qy0 = pr.y - 0.5f * pr.w;
                const float qx1 = pr.x + 0.5f * pr.z, qy1 = pr.y + 0.5f * pr.w;
                float IA, UA;
                IOU_IU(gx0, gy0, gx1, gy1, qx0, qy0, qx1, qy1,
                       (qx1 - qx0) * (qy1 - qy0), IA, UA);
                if (IA * bU0 > bI0 * UA) { bI0 = IA; bU0 = UA; bp0 = pA; }
            }
        }
        {   // combine trackers: product tie -> min p
            const float a = bI1 * bU0, c = bI0 * bU1;
            if (a > c || (a == c && bp1 < bp0)) { bI0 = bI1; bU0 = bU1; bp0 = bp1; }
        }
        for (int off = 32; off > 0; off >>= 1) {
            const float oI = __shfl_down(bI0, off);
            const float oU = __shfl_down(bU0, off);
            const int op = __shfl_down(bp0, off);
            const float a = oI * bU0, c = bI0 * oU;
            if (a > c || (a == c && op < bp0)) { bI0 = oI; bU0 = oU; bp0 = op; }
        }
        if (lane == 0) { wkI[wid] = bI0; wkU[wid] = bU0; wkP[wid] = bp0; }
        __syncthreads();
        if (tid == 0) {
            float cI = wkI[0], cU = wkU[0];
            int cp = wkP[0];
#pragma unroll
            for (int w = 1; w < 4; ++w) {
                const float a = wkI[w] * cU, c = cI * wkU[w];
                if (a > c || (a == c && wkP[w] < cp)) { cI = wkI[w]; cU = wkU[w]; cp = wkP[w]; }
            }
            sbp_g[b * NMAXn + n] = cp;
        }
    }
}

// ---------------------------------------------------------------------------
// K2 fixup (one wave per batch, SEPARATE kernel so k_neg's registers don't
// spill): stage sbp; last-n-wins; forced-delta recompute with the SAME
// cross-mult comparator; write lc[pp]=0; emit fix_*. Resets done counter.
// ---------------------------------------------------------------------------
__global__ __launch_bounds__(64) void k_fix(const float* __restrict__ conf,
                                            const float* __restrict__ loc,
                                            const float* __restrict__ priors,
                                            const float* __restrict__ labels,
                                            const int* __restrict__ objc,
                                            const int* __restrict__ sbp_g,
                                            float* __restrict__ lc,
                                            int* __restrict__ fix_np,
                                            float* __restrict__ fix_nll,
                                            float* __restrict__ fix_loc,
                                            int* __restrict__ done) {
    __shared__ int sbp[NMAXn];
    __shared__ float lab[NMAXn * 5];
    const int b = blockIdx.x;
    const int tid = threadIdx.x;  // one wave
    if (b == 0 && tid == 0) *done = 0;
    const int cnt = objc[b];
    for (int i = tid; i < NMAXn * 5; i += 64) lab[i] = labels[b * NMAXn * 5 + i];
    if (tid < cnt) sbp[tid] = sbp_g[b * NMAXn + tid];
    __syncthreads();
    bool win = false;
    if (tid < cnt) {
        const int myp = sbp[tid];
        win = true;
        for (int n2 = tid + 1; n2 < cnt; ++n2) win = win && (sbp[n2] != myp);  // last n wins
    }
    float dnll = 0.0f, dloc = 0.0f;
    int dnp = 0;
    if (win) {
        const int pp = sbp[tid];
        const float4 prf = reinterpret_cast<const float4*>(priors)[pp];
        const float qx0 = prf.x - 0.5f * prf.z, qy0 = prf.y - 0.5f * prf.w;
        const float qx1 = prf.x + 0.5f * prf.z, qy1 = prf.y + 0.5f * prf.w;
        const float qarea = (qx1 - qx0) * (qy1 - qy0);
        float bI = 0.0f, bU = 1.0f;
        int bidx2 = 0;
        for (int n2 = 0; n2 < cnt; ++n2) {  // sequential == dual-tracker combined order
            float I, U;
            IOU_IU(lab[n2 * 5 + 0], lab[n2 * 5 + 1], lab[n2 * 5 + 2],
                   lab[n2 * 5 + 3], qx0, qy0, qx1, qy1, qarea, I, U);
            if (I * bU > bI * U) { bI = I; bU = U; bidx2 = n2; }
        }
        const float* rowg = conf + ((size_t)b * Pn + pp) * Cn;
        float m2 = rowg[0];
#pragma unroll
        for (int j = 1; j < Cn; ++j) m2 = fmaxf(m2, rowg[j]);
        float ss = 0.0f;
#pragma unroll
        for (int j = 0; j < Cn; ++j) ss += __expf(rowg[j] - m2);
        const float lse = __logf(ss) + m2;
        const int ctn = (int)lab[tid * 5 + 4] + 1;
        const float4 lv = reinterpret_cast<const float4*>(loc)[(size_t)b * Pn + pp];
        dnll = lse - rowg[ctn];
        dloc = smoothl1_enc(lv, prf, lab[tid * 5 + 0], lab[tid * 5 + 1],
                            lab[tid * 5 + 2], lab[tid * 5 + 3]);
        dnp = 1;
        if (2.0f * bI >= bU) {  // old was positive: subtract its old contribution
            const int cto = (int)lab[bidx2 * 5 + 4] + 1;
            dnll -= (lse - rowg[cto]);
            dloc -= smoothl1_enc(lv, prf, lab[bidx2 * 5 + 0], lab[bidx2 * 5 + 1],
                                 lab[bidx2 * 5 + 2], lab[bidx2 * 5 + 3]);
            dnp = 0;
        }
        lc[(size_t)b * Pn + pp] = 0.0f;  // forced => positive => not a mining candidate
    }
    dnll = wave_sum_f(dnll);
    dloc = wave_sum_f(dloc);
    dnp = wave_sum_i(dnp);
    if (tid == 63) {
        fix_nll[b] = dnll;
        fix_loc[b] = dloc;
        fix_np[b] = dnp;
    }
}

// ---------------------------------------------------------------------------
// K3: per-batch hard-negative top-k sum. 256 threads x 12 float4 in registers
// (fully unrolled, no other register-heavy code in this kernel -> no spill);
// 31-iter bisection on float bits (exact); DPP reduces + 4-slot LDS combine;
// fused final reduce (adds fix_* deltas) via done counter.
// ---------------------------------------------------------------------------
__global__ __launch_bounds__(256) void k_neg(const float* __restrict__ lc,
                                             const float* __restrict__ part_loc,
                                             const float* __restrict__ part_nll,
                                             const int* __restrict__ part_np,
                                             const int* __restrict__ fix_np,
                                             const float* __restrict__ fix_nll,
                                             const float* __restrict__ fix_loc,
                                             float* __restrict__ negsum,
                                             int* __restrict__ done,
                                             float* __restrict__ out) {
    const int b = blockIdx.x;
    const int tid = threadIdx.x;
    const int lane = tid & 63, wid = tid >> 6;
    __shared__ int redc[2][4];
    __shared__ float redf[4], redf2[4];
    __shared__ int redi[4];
    __shared__ int np_sh, islast;

    const int NV = Pn / 4;  // 2183 float4s exactly
    const float4* src = reinterpret_cast<const float4*>(lc + (size_t)b * Pn);
    const float4 sent = make_float4(-1.0f, -1.0f, -1.0f, -1.0f);
    float4 rr[12];
#pragma unroll
    for (int j = 0; j < 12; ++j) {
        const int i = tid + 256 * j;
        rr[j] = (i < NV) ? src[i] : sent;
    }

    if (tid < 64) {
        int npl = (tid < PX) ? part_np[b * PX + tid] : 0;
        npl = wave_sum_i(npl);
        if (tid == 63) np_sh = npl;
    }
    __syncthreads();
    const int k = min(3 * (np_sh + fix_np[b]), Pn - 1);

    unsigned lo = 0u, hi = 0x7F800000u;
#pragma unroll 1
    for (int it = 0; it < 31; ++it) {
        const unsigned mid = lo + ((hi - lo) >> 1);
        const float fm = __uint_as_float(mid);  // fm >= 0: sentinels never counted
        int c = 0;
#pragma unroll
        for (int j = 0; j < 12; ++j)
            c += (rr[j].x >= fm) + (rr[j].y >= fm) + (rr[j].z >= fm) + (rr[j].w >= fm);
        c = wave_sum_i(c);
        if (lane == 63) redc[it & 1][wid] = c;
        __syncthreads();
        const int tot = redc[it & 1][0] + redc[it & 1][1]
                      + redc[it & 1][2] + redc[it & 1][3];
        if (tot >= k) lo = mid;
        else hi = mid;
    }
    const float v = __uint_as_float(lo);  // exact k-th largest value

    float sm = 0.0f;
    int c = 0;
#pragma unroll
    for (int j = 0; j < 12; ++j) {
        if (rr[j].x > v) { sm += rr[j].x; ++c; }
        if (rr[j].y > v) { sm += rr[j].y; ++c; }
        if (rr[j].z > v) { sm += rr[j].z; ++c; }
        if (rr[j].w > v) { sm += rr[j].w; ++c; }
    }
    sm = wave_sum_f(sm);
    c = wave_sum_i(c);
    if (lane == 63) { redf[wid] = sm; redi[wid] = c; }
    __syncthreads();
    if (tid == 0) {
        const float st = redf[0] + redf[1] + redf[2] + redf[3];
        const int ct = redi[0] + redi[1] + redi[2] + redi[3];
        negsum[b] = st + (float)(k - ct) * v;  // exact tie handling at boundary
        __threadfence();
        islast = (atomicAdd(done, 1) == Bn - 1) ? 1 : 0;
    }
    __syncthreads();
    if (!islast) return;
    __threadfence();  // acquire: other blocks' stores precede their fenced atomics

    // ---- fused final reduce (exactly one block runs this) ----
    float sl = 0.0f, sn = 0.0f;
    int np = 0;
    for (int i = tid; i < Bn * PX; i += 256) {
        sl += part_loc[i];
        sn += part_nll[i];
        np += part_np[i];
    }
    if (tid < Bn) {
        sn += negsum[tid] + fix_nll[tid];
        sl += fix_loc[tid];
        np += fix_np[tid];
    }
    sl = wave_sum_f(sl);
    sn = wave_sum_f(sn);
    np = wave_sum_i(np);
    if (lane == 63) { redf[wid] = sn; redf2[wid] = sl; redi[wid] = np; }
    __syncthreads();
    if (tid == 0) {
        const float fN = (float)(redi[0] + redi[1] + redi[2] + redi[3]);
        out[0] = (redf2[0] + redf2[1] + redf2[2] + redf2[3]) / fN;
        out[1] = (redf[0] + redf[1] + redf[2] + redf[3]) / fN;
    }
}

extern "C" void kernel_launch(void* const* d_in, const int* in_sizes, int n_in,
                              void* d_out, int out_size, void* d_ws, size_t ws_size,
                              hipStream_t stream) {
    const float* conf = (const float*)d_in[0];
    const float* loc = (const float*)d_in[1];
    const float* priors = (const float*)d_in[2];
    const float* labels = (const float*)d_in[3];
    const int* objc = (const int*)d_in[4];
    float* out = (float*)d_out;

    // ws layout: sbp_g[3200] | part_loc/nll/np[2240 each] | negsum[64] |
    //            fix_np[64] | fix_nll[64] | fix_loc[64] | lc[Bn*Pn] | done
    int* sbp_g = (int*)d_ws;
    float* part_loc = (float*)(sbp_g + Bn * NMAXn);
    float* part_nll = part_loc + Bn * PX;
    int* part_np = (int*)(part_nll + Bn * PX);
    float* negsum = (float*)(part_np + Bn * PX);
    int* fix_np = (int*)(negsum + Bn);
    float* fix_nll = (float*)(fix_np + Bn);
    float* fix_loc = fix_nll + Bn;
    float* lc = fix_loc + Bn;
    int* done = (int*)(lc + (size_t)Bn * Pn);

    k_fused<<<Bn * PX + Bn * NMAXn, 256, 0, stream>>>(conf, loc, priors, labels, objc,
                                                      lc, part_loc, part_nll, part_np,
                                                      sbp_g);
    k_fix<<<Bn, 64, 0, stream>>>(conf, loc, priors, labels, objc, sbp_g, lc,
                                 fix_np, fix_nll, fix_loc, done);
    k_neg<<<Bn, 256, 0, stream>>>(lc, part_loc, part_nll, part_np,
                                  fix_np, fix_nll, fix_loc, negsum, done, out);
}